// Round 1
// baseline (4484.697 us; speedup 1.0000x reference)
//
#include <hip/hip_runtime.h>
#include <cmath>

// VQ-VAE quantization forward: B=64, K=1024, D=128, H=W=32.
// Ref model (6 rounds of absmax triangulation): q_k = fl32(fl32(A - fl32(2*B_k)) + C_k),
// first-index argmin, where B comes from a GEMM backend: single accumulator,
// SEQUENTIAL FMA over d. A = sum(z*z,-1) sequential; C = sum(emb*emb,-1) pairwise-8.
// out0 = fl(fl(e-z)+z); out1 = e. Replicated chains pinned with empty-asm barriers.
//
// R1 restructure: z tile staged in LDS [d][px] (shared by all waves of the block),
// KSPLIT 2->8 (512-thread blocks) so occupancy is LDS-limited at 24 waves/CU
// instead of grid-limited at 8. Eliminates the zv[128] scratch array that was
// the R0 bottleneck (VGPR_Count=80 < 128 => private-memory reloads in hot loop).
// Fast-score chain order (sequential d per accumulator) is UNCHANGED.

#define D_DIM   128
#define K_CODES 1024
#define HW_SZ   1024
#define N_PIX   65536
#define OUT_OFF ((size_t)N_PIX * D_DIM)

#define KSPLIT  8
#define KPT     (K_CODES / KSPLIT)   // 128 codes per thread
#define CB      8
#define DCHUNK  16
// ref-q deviates from (A + t_fast) by <= ~2 grid roundings (3.1e-5) + chain
// noise (~1e-6). 1.2e-4 = ~3.5x margin.
#define MARGIN  1.2e-4f

// --- compiler-proof fp32 ops: result pinned in a VGPR via empty asm ---
__device__ __forceinline__ float fmul_x(float a, float b) {
    float r = a * b; asm volatile("" : "+v"(r)); return r;
}
__device__ __forceinline__ float fadd_x(float a, float b) {
    float r = a + b; asm volatile("" : "+v"(r)); return r;
}
__device__ __forceinline__ float fsub_x(float a, float b) {
    float r = a - b; asm volatile("" : "+v"(r)); return r;
}
__device__ __forceinline__ float ffma_x(float a, float b, float c) {
    float r = fmaf(a, b, c); asm volatile("" : "+v"(r)); return r;
}

__global__ __launch_bounds__(512, 6) void vq_fused(
    const float* __restrict__ z_e,
    const float* __restrict__ emb,
    float* __restrict__ out)
{
#pragma clang fp contract(off)
    __shared__ float s_z[D_DIM][64];          // 32 KB, [d][px]: 2 lanes/bank = free
    __shared__ float snorm[K_CODES];          // 4 KB
    __shared__ float s_t[KSPLIT][4][64];      // 8 KB
    __shared__ int   s_k[KSPLIT][4][64];      // 8 KB
    __shared__ int   s_kwin[64];

    const int px  = threadIdx.x;
    const int ky  = threadIdx.y;
    const int tid = ky * 64 + px;

    // C_k = np.sum(emb*emb,-1): pairwise-8 (n=128), chain identical to R0
    // (stride change only remaps k->thread, per-k chain untouched).
    for (int k = tid; k < K_CODES; k += KSPLIT * 64) {
        const float* row = emb + (size_t)k * D_DIM;
        float r[8];
        #pragma unroll
        for (int j = 0; j < 8; ++j) r[j] = fmul_x(row[j], row[j]);
        for (int i = 8; i < D_DIM; i += 8) {
            #pragma unroll
            for (int j = 0; j < 8; ++j)
                r[j] = fadd_x(r[j], fmul_x(row[i + j], row[i + j]));
        }
        const float s01 = fadd_x(r[0], r[1]), s23 = fadd_x(r[2], r[3]);
        const float s45 = fadd_x(r[4], r[5]), s67 = fadd_x(r[6], r[7]);
        snorm[k] = fadd_x(fadd_x(s01, s23), fadd_x(s45, s67));
    }

    const int p  = blockIdx.x * 64 + px;
    const int b  = p >> 10;
    const int hw = p & (HW_SZ - 1);
    const float* zp = z_e + (size_t)b * (D_DIM * HW_SZ) + hw;

    // Stage the block's z tile into LDS: wave ky loads 16 d-rows, coalesced 256B.
    #pragma unroll
    for (int jj = 0; jj < D_DIM / KSPLIT; ++jj) {
        const int d = ky * (D_DIM / KSPLIT) + jj;
        s_z[d][px] = zp[(size_t)d * HW_SZ];
    }
    __syncthreads();

    // --- hot loop: fast fmaf scores t_k = C_k - 2 z.e_k, top-4 per ky-group ---
    float t1 = __builtin_inff(), t2 = t1, t3 = t1, t4 = t1;
    int   k1 = 0, k2 = 0, k3 = 0, k4 = 0;
    const int kbase = __builtin_amdgcn_readfirstlane(ky * KPT);

    for (int kb = 0; kb < KPT; kb += CB) {
        const float* e0 = emb + (size_t)(kbase + kb) * D_DIM;  // wave-uniform -> s_load
        float acc[CB];
        #pragma unroll
        for (int c = 0; c < CB; ++c) acc[c] = 0.f;
        #pragma unroll
        for (int d0 = 0; d0 < D_DIM; d0 += DCHUNK) {
            float zc[DCHUNK];
            #pragma unroll
            for (int j = 0; j < DCHUNK; ++j) zc[j] = s_z[d0 + j][px];
            #pragma unroll
            for (int j = 0; j < DCHUNK; ++j) {
                #pragma unroll
                for (int c = 0; c < CB; ++c)
                    acc[c] = fmaf(e0[(size_t)c * D_DIM + d0 + j], zc[j], acc[c]);
            }
        }
        #pragma unroll
        for (int c = 0; c < CB; ++c) {
            const int k = kbase + kb + c;
            const float t = fmaf(-2.f, acc[c], snorm[k]);
            if (t < t4) {
                if (t < t2) {
                    t4 = t3; k4 = k3; t3 = t2; k3 = k2;
                    if (t < t1) { t2 = t1; k2 = k1; t1 = t; k1 = k; }
                    else        { t2 = t;  k2 = k; }
                } else {
                    if (t < t3) { t4 = t3; k4 = k3; t3 = t; k3 = k; }
                    else        { t4 = t;  k4 = k; }
                }
            }
        }
    }

    s_t[ky][0][px] = t1; s_t[ky][1][px] = t2; s_t[ky][2][px] = t3; s_t[ky][3][px] = t4;
    s_k[ky][0][px] = k1; s_k[ky][1][px] = k2; s_k[ky][2][px] = k3; s_k[ky][3][px] = k4;
    __syncthreads();

    if (ky == 0) {
        // A: sequential over d (value cancels per-pixel; chain kept honest anyway).
        const float z0 = s_z[0][px];
        float A32 = fmul_x(z0, z0);
        for (int d = 1; d < D_DIM; ++d) {
            const float zd = s_z[d][px];
            A32 = fadd_x(A32, fmul_x(zd, zd));
        }

        float gmin = __builtin_inff();
        #pragma unroll
        for (int c = 0; c < 4 * KSPLIT; ++c)
            gmin = fminf(gmin, s_t[c >> 2][c & 3][px]);

        // Replicated coarse q for candidates within margin; B = GEMM-style chain:
        // single accumulator, SEQUENTIAL FMA over d. Index tie-break is
        // order-independent, so candidate enumeration order doesn't matter.
        float bestq = __builtin_inff(); int bestk = 0x7fffffff;
        for (int c = 0; c < 4 * KSPLIT; ++c) {
            const float tc = s_t[c >> 2][c & 3][px];
            const int   kc = s_k[c >> 2][c & 3][px];
            if (tc <= gmin + MARGIN) {
                const float* e = emb + (size_t)kc * D_DIM;
                float B32 = 0.f;
                for (int d = 0; d < D_DIM; ++d)
                    B32 = ffma_x(s_z[d][px], e[d], B32);
                const float twoB = fmul_x(2.0f, B32);          // exact
                const float q    = fadd_x(fsub_x(A32, twoB), snorm[kc]);
                if (q < bestq || (q == bestq && kc < bestk)) { bestq = q; bestk = kc; }
            }
        }
        s_kwin[px] = bestk;
    }
    __syncthreads();

    // out0 = fl(fl(e-z)+z) (barriered), out1 = e.
    const int kwin = s_kwin[px];
    const float4* er = (const float4*)(emb + (size_t)kwin * D_DIM);
    float* o0 = out + (size_t)b * (D_DIM * HW_SZ) + hw;
    float* o1 = o0 + OUT_OFF;
    #pragma unroll
    for (int i = 0; i < 32 / KSPLIT; ++i) {
        const int d4 = ky * (32 / KSPLIT) + i;
        const float4 ev = er[d4];
        const float zx = s_z[4 * d4 + 0][px];
        const float zy = s_z[4 * d4 + 1][px];
        const float zz = s_z[4 * d4 + 2][px];
        const float zw = s_z[4 * d4 + 3][px];
        const size_t base = (size_t)(d4 * 4) * HW_SZ;
        o0[base]             = fadd_x(fsub_x(ev.x, zx), zx);
        o0[base + HW_SZ]     = fadd_x(fsub_x(ev.y, zy), zy);
        o0[base + 2 * HW_SZ] = fadd_x(fsub_x(ev.z, zz), zz);
        o0[base + 3 * HW_SZ] = fadd_x(fsub_x(ev.w, zw), zw);
        o1[base]             = ev.x;
        o1[base + HW_SZ]     = ev.y;
        o1[base + 2 * HW_SZ] = ev.z;
        o1[base + 3 * HW_SZ] = ev.w;
    }
}

extern "C" void kernel_launch(void* const* d_in, const int* in_sizes, int n_in,
                              void* d_out, int out_size, void* d_ws, size_t ws_size,
                              hipStream_t stream)
{
    const float* z_e = (const float*)d_in[0];
    const float* emb = (const float*)d_in[1];
    float* out = (float*)d_out;
    (void)in_sizes; (void)n_in; (void)out_size; (void)d_ws; (void)ws_size;

    dim3 block(64, KSPLIT, 1);
    dim3 grid(N_PIX / 64, 1, 1);
    vq_fused<<<grid, block, 0, stream>>>(z_e, emb, out);
}

// Round 2
// 1857.204 us; speedup vs baseline: 2.4148x; 2.4148x over previous
//
#include <hip/hip_runtime.h>
#include <cmath>

// VQ-VAE quantization forward: B=64, K=1024, D=128, H=W=32.
// Ref model (6 rounds of absmax triangulation): q_k = fl32(fl32(A - fl32(2*B_k)) + C_k),
// first-index argmin, where B comes from a GEMM backend: single accumulator,
// SEQUENTIAL FMA over d. A = sum(z*z,-1) sequential; C = sum(emb*emb,-1) pairwise-8.
// out0 = fl(fl(e-z)+z); out1 = e. Replicated chains pinned with empty-asm barriers.
//
// R2: R1's structure (z tile in LDS [d][px], KSPLIT=8, 512-thread blocks) was
// sound; the regression was __launch_bounds__(512,6) driving the VGPR target to
// 40 (< hot-loop live set) => zc/acc spilled to scratch => 10 GB of HBM scratch
// traffic (FETCH 8.8 GB, WRITE 1.2 GB, 9x output size). Fix: (512,2) register
// budget (cap >=128, live set ~60, zero spill) + CB 8->16 so one z pass feeds
// 2048 FMAs (LDS read demand below VALU issue). All FP chains bit-identical to
// the validated kernel: per-code score = sequential FMA over d, top-4 per
// 128-code slice, exact replicated refinement within MARGIN.

#define D_DIM   128
#define K_CODES 1024
#define HW_SZ   1024
#define N_PIX   65536
#define OUT_OFF ((size_t)N_PIX * D_DIM)

#define KSPLIT  8
#define KPT     (K_CODES / KSPLIT)   // 128 codes per ky-slice
#define CB      16                   // codes scored per z-pass
#define DCHUNK  16
// ref-q deviates from (A + t_fast) by <= ~2 grid roundings (3.1e-5) + chain
// noise (~1e-6). 1.2e-4 = ~3.5x margin.
#define MARGIN  1.2e-4f

// --- compiler-proof fp32 ops: result pinned in a VGPR via empty asm ---
__device__ __forceinline__ float fmul_x(float a, float b) {
    float r = a * b; asm volatile("" : "+v"(r)); return r;
}
__device__ __forceinline__ float fadd_x(float a, float b) {
    float r = a + b; asm volatile("" : "+v"(r)); return r;
}
__device__ __forceinline__ float fsub_x(float a, float b) {
    float r = a - b; asm volatile("" : "+v"(r)); return r;
}
__device__ __forceinline__ float ffma_x(float a, float b, float c) {
    float r = fmaf(a, b, c); asm volatile("" : "+v"(r)); return r;
}

__global__ __launch_bounds__(512, 2) void vq_fused(
    const float* __restrict__ z_e,
    const float* __restrict__ emb,
    float* __restrict__ out)
{
#pragma clang fp contract(off)
    __shared__ float s_z[D_DIM][64];          // 32 KB, [d][px]: 2 lanes/bank = free
    __shared__ float snorm[K_CODES];          // 4 KB
    __shared__ float s_t[KSPLIT][4][64];      // 8 KB
    __shared__ int   s_k[KSPLIT][4][64];      // 8 KB
    __shared__ int   s_kwin[64];

    const int px  = threadIdx.x;
    const int ky  = threadIdx.y;
    const int tid = ky * 64 + px;

    // C_k = np.sum(emb*emb,-1): pairwise-8 (n=128), per-row chain identical to
    // the validated kernel (k->thread mapping irrelevant to the chain).
    for (int k = tid; k < K_CODES; k += KSPLIT * 64) {
        const float* row = emb + (size_t)k * D_DIM;
        float r[8];
        #pragma unroll
        for (int j = 0; j < 8; ++j) r[j] = fmul_x(row[j], row[j]);
        for (int i = 8; i < D_DIM; i += 8) {
            #pragma unroll
            for (int j = 0; j < 8; ++j)
                r[j] = fadd_x(r[j], fmul_x(row[i + j], row[i + j]));
        }
        const float s01 = fadd_x(r[0], r[1]), s23 = fadd_x(r[2], r[3]);
        const float s45 = fadd_x(r[4], r[5]), s67 = fadd_x(r[6], r[7]);
        snorm[k] = fadd_x(fadd_x(s01, s23), fadd_x(s45, s67));
    }

    const int p  = blockIdx.x * 64 + px;
    const int b  = p >> 10;
    const int hw = p & (HW_SZ - 1);
    const float* zp = z_e + (size_t)b * (D_DIM * HW_SZ) + hw;

    // Stage the block's z tile into LDS: wave ky loads 16 d-rows, coalesced 256B.
    #pragma unroll
    for (int jj = 0; jj < D_DIM / KSPLIT; ++jj) {
        const int d = ky * (D_DIM / KSPLIT) + jj;
        s_z[d][px] = zp[(size_t)d * HW_SZ];
    }
    __syncthreads();

    // --- hot loop: fast fmaf scores t_k = C_k - 2 z.e_k, top-4 per ky-slice ---
    float t1 = __builtin_inff(), t2 = t1, t3 = t1, t4 = t1;
    int   k1 = 0, k2 = 0, k3 = 0, k4 = 0;
    const int kbase = __builtin_amdgcn_readfirstlane(ky * KPT);

    #pragma unroll 1
    for (int kb = 0; kb < KPT; kb += CB) {
        const float* e0 = emb + (size_t)(kbase + kb) * D_DIM;  // wave-uniform -> s_load
        float acc[CB];
        #pragma unroll
        for (int c = 0; c < CB; ++c) acc[c] = 0.f;
        #pragma unroll
        for (int d0 = 0; d0 < D_DIM; d0 += DCHUNK) {
            float zc[DCHUNK];
            #pragma unroll
            for (int j = 0; j < DCHUNK; ++j) zc[j] = s_z[d0 + j][px];
            #pragma unroll
            for (int j = 0; j < DCHUNK; ++j) {
                #pragma unroll
                for (int c = 0; c < CB; ++c)
                    acc[c] = fmaf(e0[(size_t)c * D_DIM + d0 + j], zc[j], acc[c]);
            }
        }
        #pragma unroll
        for (int c = 0; c < CB; ++c) {
            const int k = kbase + kb + c;
            const float t = fmaf(-2.f, acc[c], snorm[k]);
            if (t < t4) {
                if (t < t2) {
                    t4 = t3; k4 = k3; t3 = t2; k3 = k2;
                    if (t < t1) { t2 = t1; k2 = k1; t1 = t; k1 = k; }
                    else        { t2 = t;  k2 = k; }
                } else {
                    if (t < t3) { t4 = t3; k4 = k3; t3 = t; k3 = k; }
                    else        { t4 = t;  k4 = k; }
                }
            }
        }
    }

    s_t[ky][0][px] = t1; s_t[ky][1][px] = t2; s_t[ky][2][px] = t3; s_t[ky][3][px] = t4;
    s_k[ky][0][px] = k1; s_k[ky][1][px] = k2; s_k[ky][2][px] = k3; s_k[ky][3][px] = k4;
    __syncthreads();

    if (ky == 0) {
        // A: sequential over d (value cancels per-pixel; chain kept honest anyway).
        const float z0 = s_z[0][px];
        float A32 = fmul_x(z0, z0);
        for (int d = 1; d < D_DIM; ++d) {
            const float zd = s_z[d][px];
            A32 = fadd_x(A32, fmul_x(zd, zd));
        }

        float gmin = __builtin_inff();
        #pragma unroll
        for (int c = 0; c < 4 * KSPLIT; ++c)
            gmin = fminf(gmin, s_t[c >> 2][c & 3][px]);

        // Replicated coarse q for candidates within margin; B = GEMM-style chain:
        // single accumulator, SEQUENTIAL FMA over d. Index tie-break is
        // order-independent, so candidate enumeration order doesn't matter.
        float bestq = __builtin_inff(); int bestk = 0x7fffffff;
        for (int c = 0; c < 4 * KSPLIT; ++c) {
            const float tc = s_t[c >> 2][c & 3][px];
            const int   kc = s_k[c >> 2][c & 3][px];
            if (tc <= gmin + MARGIN) {
                const float* e = emb + (size_t)kc * D_DIM;
                float B32 = 0.f;
                for (int d = 0; d < D_DIM; ++d)
                    B32 = ffma_x(s_z[d][px], e[d], B32);
                const float twoB = fmul_x(2.0f, B32);          // exact
                const float q    = fadd_x(fsub_x(A32, twoB), snorm[kc]);
                if (q < bestq || (q == bestq && kc < bestk)) { bestq = q; bestk = kc; }
            }
        }
        s_kwin[px] = bestk;
    }
    __syncthreads();

    // out0 = fl(fl(e-z)+z) (barriered), out1 = e.
    const int kwin = s_kwin[px];
    const float4* er = (const float4*)(emb + (size_t)kwin * D_DIM);
    float* o0 = out + (size_t)b * (D_DIM * HW_SZ) + hw;
    float* o1 = o0 + OUT_OFF;
    #pragma unroll
    for (int i = 0; i < 32 / KSPLIT; ++i) {
        const int d4 = ky * (32 / KSPLIT) + i;
        const float4 ev = er[d4];
        const float zx = s_z[4 * d4 + 0][px];
        const float zy = s_z[4 * d4 + 1][px];
        const float zz = s_z[4 * d4 + 2][px];
        const float zw = s_z[4 * d4 + 3][px];
        const size_t base = (size_t)(d4 * 4) * HW_SZ;
        o0[base]             = fadd_x(fsub_x(ev.x, zx), zx);
        o0[base + HW_SZ]     = fadd_x(fsub_x(ev.y, zy), zy);
        o0[base + 2 * HW_SZ] = fadd_x(fsub_x(ev.z, zz), zz);
        o0[base + 3 * HW_SZ] = fadd_x(fsub_x(ev.w, zw), zw);
        o1[base]             = ev.x;
        o1[base + HW_SZ]     = ev.y;
        o1[base + 2 * HW_SZ] = ev.z;
        o1[base + 3 * HW_SZ] = ev.w;
    }
}

extern "C" void kernel_launch(void* const* d_in, const int* in_sizes, int n_in,
                              void* d_out, int out_size, void* d_ws, size_t ws_size,
                              hipStream_t stream)
{
    const float* z_e = (const float*)d_in[0];
    const float* emb = (const float*)d_in[1];
    float* out = (float*)d_out;
    (void)in_sizes; (void)n_in; (void)out_size; (void)d_ws; (void)ws_size;

    dim3 block(64, KSPLIT, 1);
    dim3 grid(N_PIX / 64, 1, 1);
    vq_fused<<<grid, block, 0, stream>>>(z_e, emb, out);
}

// Round 3
// 973.896 us; speedup vs baseline: 4.6049x; 1.9070x over previous
//
#include <hip/hip_runtime.h>
#include <cmath>

// VQ-VAE quantization forward: B=64, K=1024, D=128, H=W=32.
// Ref model (6 rounds of absmax triangulation): q_k = fl32(fl32(A - fl32(2*B_k)) + C_k),
// first-index argmin, where B comes from a GEMM backend: single accumulator,
// SEQUENTIAL FMA over d. A = sum(z*z,-1) sequential; C = sum(emb*emb,-1) pairwise-8.
// out0 = fl(fl(e-z)+z); out1 = e. Replicated chains pinned with empty-asm barriers.
//
// R3: R0/R2 shared the same e-feed bottleneck — wave-uniform s_loads (8KB bursts
// vs ~100 SGPRs) serialized against z ds_reads on the shared lgkmcnt counter
// (VALU-active 620-668us in both, 36-44% busy, 24% occupancy). Restructure:
//  * 128 px/block, 2 px/thread; all 8 waves share a 64-code e-chunk staged in
//    LDS (16 chunks; prefetch->regs during compute, ds_write after barrier).
//  * e reads are broadcast ds_read_b128 (uniform addr, conflict-free); each
//    e-granule feeds 8 FMAs (2px x 4d) so the loop stays VALU-bound even at
//    full-rate b128 cost.
//  * z transposed into padded s_zT[128][132] => per-lane ds_read_b128,
//    row stride 33 granules == conflict-free (lane%8 quad spread).
//  * s_t/s_k alias the dead e-chunk buffer for the cross-wave reduce.
// FP chains bit-identical to the validated kernel: fast score = single-acc
// sequential-FMA over ascending d (d=4g+j), top-4 per 128-code-per-thread
// subset + MARGIN, exact replicated refinement, snorm pairwise-8, pinned
// A/B/output chains.

#define D_DIM   128
#define K_CODES 1024
#define HW_SZ   1024
#define N_PIX   65536
#define OUT_OFF ((size_t)N_PIX * D_DIM)

#define PXB     128                     // pixels per block
#define NW      8                       // waves per block
#define CHUNK_K 64                      // codes staged per chunk
#define NCHUNK  (K_CODES / CHUNK_K)     // 16
#define CPT     (CHUNK_K / NW)          // 8 codes per thread per chunk
#define ZLD     132                     // padded row: 33 granules, conflict-free b128
// ref-q deviates from (A + t_fast) by <= ~2 grid roundings (3.1e-5) + chain
// noise (~1e-6). 1.2e-4 = ~3.5x margin.
#define MARGIN  1.2e-4f

typedef float f32x4 __attribute__((ext_vector_type(4)));

// --- compiler-proof fp32 ops: result pinned in a VGPR via empty asm ---
__device__ __forceinline__ float fmul_x(float a, float b) {
    float r = a * b; asm volatile("" : "+v"(r)); return r;
}
__device__ __forceinline__ float fadd_x(float a, float b) {
    float r = a + b; asm volatile("" : "+v"(r)); return r;
}
__device__ __forceinline__ float fsub_x(float a, float b) {
    float r = a - b; asm volatile("" : "+v"(r)); return r;
}
__device__ __forceinline__ float ffma_x(float a, float b, float c) {
    float r = fmaf(a, b, c); asm volatile("" : "+v"(r)); return r;
}

__global__ __launch_bounds__(512, 2) void vq_fused(
    const float* __restrict__ z_e,
    const float* __restrict__ emb,
    float* __restrict__ out)
{
#pragma clang fp contract(off)
    __shared__ float s_zT[PXB][ZLD];            // 66 KB, [px][d] padded
    __shared__ float e_u[CHUNK_K * D_DIM];      // 32 KB e-chunk; aliased s_t/s_k later
    __shared__ float snorm[K_CODES];            // 4 KB
    __shared__ int   s_kwin[PXB];               // 0.5 KB

    const int px  = threadIdx.x;                // lane 0..63
    const int ky  = threadIdx.y;                // wave 0..7
    const int tid = ky * 64 + px;

    const int p0  = blockIdx.x * PXB;
    const int b   = p0 >> 10;
    const int hw0 = p0 & (HW_SZ - 1);
    const float* zbase = z_e + (size_t)b * (D_DIM * HW_SZ) + hw0;

    // ---- z stage: global [d][128 px] -> s_zT[px][d] (transpose) ----
    #pragma unroll
    for (int r = 0; r < 8; ++r) {
        const int idx = r * 512 + tid;          // 0..4095
        const int d   = idx >> 5;               // 0..127
        const int i4  = (idx & 31) * 4;         // pixel group
        const f32x4 v = *(const f32x4*)(zbase + (size_t)d * HW_SZ + i4);
        s_zT[i4 + 0][d] = v[0];
        s_zT[i4 + 1][d] = v[1];
        s_zT[i4 + 2][d] = v[2];
        s_zT[i4 + 3][d] = v[3];
    }

    // ---- C_k = np.sum(emb*emb,-1): pairwise-8 (n=128), chain verbatim ----
    for (int k = tid; k < K_CODES; k += NW * 64) {
        const float* row = emb + (size_t)k * D_DIM;
        float r[8];
        #pragma unroll
        for (int j = 0; j < 8; ++j) r[j] = fmul_x(row[j], row[j]);
        for (int i = 8; i < D_DIM; i += 8) {
            #pragma unroll
            for (int j = 0; j < 8; ++j)
                r[j] = fadd_x(r[j], fmul_x(row[i + j], row[i + j]));
        }
        const float s01 = fadd_x(r[0], r[1]), s23 = fadd_x(r[2], r[3]);
        const float s45 = fadd_x(r[4], r[5]), s67 = fadd_x(r[6], r[7]);
        snorm[k] = fadd_x(fadd_x(s01, s23), fadd_x(s45, s67));
    }

    // ---- prefetch chunk 0 into regs ----
    f32x4 stg0, stg1, stg2, stg3;
    {
        const float* g = emb + (size_t)tid * 4;
        stg0 = *(const f32x4*)(g);
        stg1 = *(const f32x4*)(g + 2048);
        stg2 = *(const f32x4*)(g + 4096);
        stg3 = *(const f32x4*)(g + 6144);
    }
    __syncthreads();                            // z + snorm visible
    {
        float* w = e_u + tid * 4;
        *(f32x4*)(w)        = stg0;
        *(f32x4*)(w + 2048) = stg1;
        *(f32x4*)(w + 4096) = stg2;
        *(f32x4*)(w + 6144) = stg3;
    }
    __syncthreads();                            // chunk 0 staged

    // top-4 state for 2 pixels (all indices compile-time constant)
    float tt[2][4]; int kk[2][4];
    #pragma unroll
    for (int pp = 0; pp < 2; ++pp) {
        #pragma unroll
        for (int s = 0; s < 4; ++s) { tt[pp][s] = __builtin_inff(); kk[pp][s] = 0; }
    }

    const int ccb = ky * CPT;                   // this wave's codes within chunk

    #pragma unroll 1
    for (int chunk = 0; chunk < NCHUNK; ++chunk) {
        // prefetch next chunk (VMEM in flight under compute)
        if (chunk + 1 < NCHUNK) {
            const float* g = emb + (size_t)(chunk + 1) * (CHUNK_K * D_DIM) + (size_t)tid * 4;
            stg0 = *(const f32x4*)(g);
            stg1 = *(const f32x4*)(g + 2048);
            stg2 = *(const f32x4*)(g + 4096);
            stg3 = *(const f32x4*)(g + 6144);
        }

        // ---- fast scores: acc[c][pp] = sum_d e*z, sequential ascending d ----
        float acc[CPT][2];
        #pragma unroll
        for (int c = 0; c < CPT; ++c) { acc[c][0] = 0.f; acc[c][1] = 0.f; }

        #pragma unroll 4
        for (int g = 0; g < 32; ++g) {
            const f32x4 za = *(const f32x4*)&s_zT[px][4 * g];
            const f32x4 zb = *(const f32x4*)&s_zT[px + 64][4 * g];
            #pragma unroll
            for (int c = 0; c < CPT; ++c) {
                const f32x4 e4 = *(const f32x4*)&e_u[(ccb + c) * D_DIM + 4 * g];
                #pragma unroll
                for (int j = 0; j < 4; ++j) {    // d = 4g+j ascending: chain preserved
                    acc[c][0] = fmaf(e4[j], za[j], acc[c][0]);
                    acc[c][1] = fmaf(e4[j], zb[j], acc[c][1]);
                }
            }
        }

        // ---- selection: t = C_k - 2*acc, top-4 per thread-subset per pixel ----
        #pragma unroll
        for (int c = 0; c < CPT; ++c) {
            const int k = chunk * CHUNK_K + ccb + c;
            const float sn = snorm[k];
            #pragma unroll
            for (int pp = 0; pp < 2; ++pp) {
                const float t = fmaf(-2.f, acc[c][pp], sn);
                if (t < tt[pp][3]) {
                    if (t < tt[pp][1]) {
                        tt[pp][3] = tt[pp][2]; kk[pp][3] = kk[pp][2];
                        tt[pp][2] = tt[pp][1]; kk[pp][2] = kk[pp][1];
                        if (t < tt[pp][0]) {
                            tt[pp][1] = tt[pp][0]; kk[pp][1] = kk[pp][0];
                            tt[pp][0] = t; kk[pp][0] = k;
                        } else { tt[pp][1] = t; kk[pp][1] = k; }
                    } else {
                        if (t < tt[pp][2]) {
                            tt[pp][3] = tt[pp][2]; kk[pp][3] = kk[pp][2];
                            tt[pp][2] = t; kk[pp][2] = k;
                        } else { tt[pp][3] = t; kk[pp][3] = k; }
                    }
                }
            }
        }

        __syncthreads();                        // everyone done reading e_u
        if (chunk + 1 < NCHUNK) {
            float* w = e_u + tid * 4;
            *(f32x4*)(w)        = stg0;
            *(f32x4*)(w + 2048) = stg1;
            *(f32x4*)(w + 4096) = stg2;
            *(f32x4*)(w + 6144) = stg3;
            __syncthreads();                    // next chunk staged
        }
    }

    // ---- cross-wave reduce: alias s_t/s_k over the dead e-chunk buffer ----
    float* s_t = e_u;                           // [NW*4][PXB] floats
    int*   s_k = (int*)(e_u + NW * 4 * PXB);    // [NW*4][PXB] ints
    #pragma unroll
    for (int s = 0; s < 4; ++s) {
        s_t[(ky * 4 + s) * PXB + px]      = tt[0][s];
        s_t[(ky * 4 + s) * PXB + px + 64] = tt[1][s];
        s_k[(ky * 4 + s) * PXB + px]      = kk[0][s];
        s_k[(ky * 4 + s) * PXB + px + 64] = kk[1][s];
    }
    __syncthreads();

    if (ky == 0) {
        #pragma unroll 1
        for (int pp = 0; pp < 2; ++pp) {
            const int p = px + pp * 64;
            // A: sequential over d (value cancels per-pixel; chain kept honest).
            const float z0 = s_zT[p][0];
            float A32 = fmul_x(z0, z0);
            for (int d = 1; d < D_DIM; ++d) {
                const float zd = s_zT[p][d];
                A32 = fadd_x(A32, fmul_x(zd, zd));
            }

            float gmin = __builtin_inff();
            #pragma unroll
            for (int c = 0; c < 4 * NW; ++c)
                gmin = fminf(gmin, s_t[c * PXB + p]);

            // Replicated coarse q for candidates within margin; B = GEMM-style
            // chain: single accumulator, SEQUENTIAL FMA over d. Index tie-break
            // is order-independent.
            float bestq = __builtin_inff(); int bestk = 0x7fffffff;
            for (int c = 0; c < 4 * NW; ++c) {
                const float tc = s_t[c * PXB + p];
                const int   kc = s_k[c * PXB + p];
                if (tc <= gmin + MARGIN) {
                    const float* e = emb + (size_t)kc * D_DIM;
                    float B32 = 0.f;
                    for (int d = 0; d < D_DIM; ++d)
                        B32 = ffma_x(s_zT[p][d], e[d], B32);
                    const float twoB = fmul_x(2.0f, B32);      // exact
                    const float q    = fadd_x(fsub_x(A32, twoB), snorm[kc]);
                    if (q < bestq || (q == bestq && kc < bestk)) { bestq = q; bestk = kc; }
                }
            }
            s_kwin[p] = bestk;
        }
    }
    __syncthreads();

    // ---- epilogue: out0 = fl(fl(e-z)+z) (pinned), out1 = e ----
    const int p  = tid & 127;                   // pixel
    const int dg = tid >> 7;                    // d-quarter 0..3
    const int kwin = s_kwin[p];
    const float* er = emb + (size_t)kwin * D_DIM + dg * 32;
    float* o0 = out + (size_t)b * (D_DIM * HW_SZ) + hw0 + p;
    float* o1 = o0 + OUT_OFF;
    #pragma unroll
    for (int i = 0; i < 8; ++i) {
        const f32x4 e4 = *(const f32x4*)(er + i * 4);
        #pragma unroll
        for (int j = 0; j < 4; ++j) {
            const int d = dg * 32 + i * 4 + j;
            const float zv = s_zT[p][d];
            o0[(size_t)d * HW_SZ] = fadd_x(fsub_x(e4[j], zv), zv);
            o1[(size_t)d * HW_SZ] = e4[j];
        }
    }
}

extern "C" void kernel_launch(void* const* d_in, const int* in_sizes, int n_in,
                              void* d_out, int out_size, void* d_ws, size_t ws_size,
                              hipStream_t stream)
{
    const float* z_e = (const float*)d_in[0];
    const float* emb = (const float*)d_in[1];
    float* out = (float*)d_out;
    (void)in_sizes; (void)n_in; (void)out_size; (void)d_ws; (void)ws_size;

    dim3 block(64, NW, 1);
    dim3 grid(N_PIX / PXB, 1, 1);
    vq_fused<<<grid, block, 0, stream>>>(z_e, emb, out);
}